// Round 6
// baseline (136.600 us; speedup 1.0000x reference)
//
#include <hip/hip_runtime.h>
#include <hip/hip_bf16.h>
#include <stdint.h>
#include <math.h>

#define NROWS 8192
#define DIM   256
#define RB    256          // row bytes (fp8)
#define BI    128          // i rows per tile block
#define JSUB  32           // j rows per sub-tile (LDS double-buffered)
#define NBJS  8
#define JBLK  (JSUB*NBJS)  // 256 j rows per tile block
#define NG    (NROWS/JBLK) // 32
#define NIT   (NROWS/BI)   // 64
#define NCLS  64
#define CAP   256          // max class members (mean 128)

typedef __attribute__((ext_vector_type(4)))  int   int4v;
typedef __attribute__((ext_vector_type(8)))  int   int8v;
typedef __attribute__((ext_vector_type(16))) float floatx16;

typedef const __attribute__((address_space(1))) uint32_t gas_u32;
typedef __attribute__((address_space(3))) uint32_t las_u32;

#define SCALE_1_16 0x7B7B7B7B          // E8M0 123 = 2^-4 in every byte
#define L2E10      14.4269504088896f   // 10 * log2(e)
#define CA_SCALE   (L2E10 * 16.0f)     // A-side fp8 pre-scale -> acc = L2E10*cos
#define CB_SCALE   16.0f               // B-side fp8 pre-scale

#if __has_builtin(__builtin_amdgcn_exp2f)
#define EXP2(x) __builtin_amdgcn_exp2f(x)   // raw v_exp_f32; inputs <= 14.43, safe
#else
#define EXP2(x) exp2f(x)
#endif

__device__ __forceinline__ void gload_lds16(const void* g, void* l) {
    // LDS dest = wave-uniform base + lane*16 ; global src per-lane
    __builtin_amdgcn_global_load_lds((gas_u32*)(uintptr_t)g,
                                     (las_u32*)(uintptr_t)l, 16, 0, 0);
}

// ---- Kernel 1: row-normalize fp32 -> two fp8 e4m3 arrays (A: x230.83, B: x16) ----
// acc = (CA*e_j)*(CB*e_i)*2^-8 = 14.4269*cos  -> epilogue needs no fma, no offset.
__global__ __launch_bounds__(256) void normalize_kernel(const float* __restrict__ emb,
                                                        uint32_t* __restrict__ a8,
                                                        uint32_t* __restrict__ b8,
                                                        float* __restrict__ out)
{
    if (blockIdx.x == 0 && threadIdx.x == 0) *out = 0.f;   // replaces memset dispatch
    int row  = blockIdx.x * 4 + (threadIdx.x >> 6);
    int lane = threadIdx.x & 63;
    float4 v = ((const float4*)(emb + (size_t)row * DIM))[lane];
    float ss = v.x*v.x + v.y*v.y + v.z*v.z + v.w*v.w;
    #pragma unroll
    for (int off = 32; off > 0; off >>= 1)
        ss += __shfl_xor(ss, off, 64);
    float inv = 1.0f / fmaxf(sqrtf(ss), 1e-8f);
    float ia = CA_SCALE * inv, ib = CB_SCALE * inv;
    int ra = __builtin_amdgcn_cvt_pk_fp8_f32(v.x * ia, v.y * ia, 0, false);
    ra     = __builtin_amdgcn_cvt_pk_fp8_f32(v.z * ia, v.w * ia, ra, true);
    int rb = __builtin_amdgcn_cvt_pk_fp8_f32(v.x * ib, v.y * ib, 0, false);
    rb     = __builtin_amdgcn_cvt_pk_fp8_f32(v.z * ib, v.w * ib, rb, true);
    a8[(size_t)row * 64 + lane] = (uint32_t)ra;
    b8[(size_t)row * 64 + lane] = (uint32_t)rb;
}

// ---- Kernel 2 (fused): blocks 0..63 = per-class positives; blocks 64+ = neg/total tiles ----
template<bool DIAG>
__device__ __forceinline__ void epi1(const floatx16& a, int jbase, int h, int ic, float& ts)
{
    #pragma unroll
    for (int rq = 0; rq < 4; ++rq)
        #pragma unroll
        for (int r2 = 0; r2 < 4; ++r2) {
            float v = EXP2(a[rq * 4 + r2]);   // acc already = L2E10*cos
            if (DIAG) {
                const int jg_ = jbase + rq * 8 + h * 4 + r2;
                if (jg_ == ic) v = 0.f;       // exclude diagonal
            }
            ts += v;
        }
}

// 16 KB LDS/block + <=64 VGPR -> 8 blocks/CU, 32 waves/CU (2x the 83.3us baseline's
// latency-hiding). Grid 2048 neg blocks = fully resident. Inner loop == baseline.
__global__ __launch_bounds__(256, 8) void fused_kernel(const uint8_t* __restrict__ eA,
                                                       const uint8_t* __restrict__ eB,
                                                       const int* __restrict__ tgt,
                                                       float* __restrict__ pts,
                                                       float* __restrict__ sp)
{
    __shared__ uint8_t smem[2 * JSUB * RB];   // 16 KB: tile A dbuf / pos idx scratch

    const int tid  = threadIdx.x;
    const int wave = tid >> 6;
    const int lane = tid & 63;
    const int col  = lane & 31;
    const int h    = lane >> 5;

    if (blockIdx.x < NCLS) {
        // ================= positives path (one block per class) =================
        int* idx = (int*)smem;
        int* cnt = (int*)(smem + CAP * 4);
        const int c = blockIdx.x;
        if (tid == 0) *cnt = 0;
        __syncthreads();
        // scan all targets (coalesced int4 loads, batched for latency)
        int4v tv[8];
        #pragma unroll
        for (int k = 0; k < 8; ++k)
            tv[k] = *(const int4v*)(tgt + k * 1024 + tid * 4);
        #pragma unroll
        for (int k = 0; k < 8; ++k)
            #pragma unroll
            for (int r = 0; r < 4; ++r)
                if (tv[k][r] == c) {
                    int p = atomicAdd(cnt, 1);
                    if (p < CAP) idx[p] = k * 1024 + tid * 4 + r;
                }
        __syncthreads();
        const int M   = min(*cnt, CAP);
        const int Mp  = (M + 31) & ~31;
        const int nbt = Mp >> 5;

        // fragments straight from L2 (f8f6f4 layout: lane row=col, k [s*64+h*32,+32))
        for (int bt = wave; bt < nbt; bt += 4) {
            const int b = bt * 32 + col;
            const uint8_t* pb = eB + (size_t)idx[min(b, M - 1)] * RB + h * 32;
            int8v bfr[4];
            #pragma unroll
            for (int s = 0; s < 4; ++s)
                bfr[s] = *(const int8v*)(pb + s * 64);
            float psum = 0.f;
            for (int at = 0; at < nbt; ++at) {
                const uint8_t* pa = eA + (size_t)idx[min(at * 32 + col, M - 1)] * RB + h * 32;
                floatx16 acc = (floatx16){0.f,0.f,0.f,0.f,0.f,0.f,0.f,0.f,
                                          0.f,0.f,0.f,0.f,0.f,0.f,0.f,0.f};
                #pragma unroll
                for (int s = 0; s < 4; ++s) {
                    int8v af = *(const int8v*)(pa + s * 64);
                    acc = __builtin_amdgcn_mfma_scale_f32_32x32x64_f8f6f4(
                        af, bfr[s], acc, 0, 0, 0, SCALE_1_16, 0, SCALE_1_16);
                }
                #pragma unroll
                for (int rq = 0; rq < 4; ++rq)
                    #pragma unroll
                    for (int r2 = 0; r2 < 4; ++r2) {
                        const int a = at * 32 + rq * 8 + h * 4 + r2;
                        float v = EXP2(acc[rq * 4 + r2]);
                        psum += (a != b && a < M) ? v : 0.f;   // exact diag/pad mask
                    }
            }
            psum += __shfl_xor(psum, 32, 64);   // h-halves: disjoint a's, same b
            if (h == 0 && b < M) sp[idx[b]] = psum;
        }
        return;
    }

    // ================= negatives/total tile path =================
    const int g  = blockIdx.x - NCLS;
    const int bi = g & (NIT - 1);
    const int jg = g >> 6;            // 0..NG-1

    // B fragments straight from global to registers, once per block (L2-hit)
    const uint8_t* pb = eB + (size_t)(bi * BI + wave * 32 + col) * RB + h * 32;
    int8v bfr[4];
    #pragma unroll
    for (int s = 0; s < 4; ++s)
        bfr[s] = *(const int8v*)(pb + s * 64);

    // A staging map (mod-16 xor swizzle on 16B chunks of 256B rows)
    // 8 KB/stage = 512 chunks = 2 per thread
    int goffA[2];
    #pragma unroll
    for (int t = 0; t < 2; ++t) {
        int s   = wave * 128 + t * 64 + lane;
        int row = s >> 4;
        int lc  = (s & 15) ^ (row & 15);
        goffA[t] = row * RB + lc * 16;
    }
    const char* gA = (const char*)(eA + (size_t)jg * JBLK * RB);

    #pragma unroll
    for (int t = 0; t < 2; ++t)
        gload_lds16(gA + goffA[t], smem + wave * 2048 + t * 1024);

    const int ic0 = bi * BI + wave * 32 + col;   // this lane's i

    const int xm = col & 15;
    int poff[4];
    #pragma unroll
    for (int s = 0; s < 4; ++s)
        poff[s] = ((s * 4 + h * 2) ^ xm) << 4;   // partner chunk = poff[s]^16

    __syncthreads();   // drains A0 DMA

    float ts = 0.f;
    // diagonal: block j-range [jg*256,+256); overlap with i-range [bi*128,+128)
    // at phases bjs where bjs>>2 == bi - 2*jg
    const int dquad = bi - 2 * jg;

    #pragma unroll
    for (int bjs = 0; bjs < NBJS; ++bjs) {
        if (bjs < NBJS - 1) {   // issue next A stage; drains at phase-end barrier
            const char* gAn = gA + (size_t)(bjs + 1) * JSUB * RB;
            #pragma unroll
            for (int t = 0; t < 2; ++t)
                gload_lds16(gAn + goffA[t],
                            smem + ((bjs + 1) & 1) * (JSUB * RB) + wave * 2048 + t * 1024);
        }

        const uint8_t* ab = smem + (bjs & 1) * (JSUB * RB);
        floatx16 acc = (floatx16){0.f,0.f,0.f,0.f,0.f,0.f,0.f,0.f,
                                  0.f,0.f,0.f,0.f,0.f,0.f,0.f,0.f};

        #pragma unroll
        for (int s = 0; s < 4; ++s) {
            const uint8_t* pa = ab + (size_t)col * RB;
            int4v lo = *(const int4v*)(pa + poff[s]);
            int4v hi = *(const int4v*)(pa + (poff[s] ^ 16));
            int8v af = __builtin_shufflevector(lo, hi, 0, 1, 2, 3, 4, 5, 6, 7);
            acc = __builtin_amdgcn_mfma_scale_f32_32x32x64_f8f6f4(
                af, bfr[s], acc, 0, 0, 0, SCALE_1_16, 0, SCALE_1_16);
        }

        const int jbs = jg * JBLK + bjs * JSUB;
        if ((bjs >> 2) == dquad)
            epi1<true >(acc, jbs, h, ic0, ts);
        else
            epi1<false>(acc, jbs, h, ic0, ts);

        if (bjs < NBJS - 1)
            __syncthreads();   // drains next-A DMA; guards restage of buffer just read
    }

    ts += __shfl_xor(ts, 32, 64);   // L and L+32: same i, disjoint j-halves
    if (h == 0)
        pts[(size_t)jg * NROWS + ic0] = ts;
}

// ---- Kernel 3: per-row log-diff + global sum ----
__global__ __launch_bounds__(256) void finalize_kernel(const float* __restrict__ pts,
                                                       const float* __restrict__ sp,
                                                       float* __restrict__ out)
{
    const int i = blockIdx.x * 256 + threadIdx.x;
    float st = 0.f;
    #pragma unroll
    for (int t = 0; t < NG; ++t)
        st += pts[(size_t)t * NROWS + i];
    const float spv = sp[i];
    const float ns  = st - spv;          // negatives = total - positives (diag-free both)
    float loss = logf(ns) - logf(spv);
    #pragma unroll
    for (int off = 32; off > 0; off >>= 1)
        loss += __shfl_xor(loss, off, 64);
    __shared__ float w4[4];
    if ((threadIdx.x & 63) == 0) w4[threadIdx.x >> 6] = loss;
    __syncthreads();
    if (threadIdx.x == 0)
        atomicAdd(out, w4[0] + w4[1] + w4[2] + w4[3]);
}

extern "C" void kernel_launch(void* const* d_in, const int* in_sizes, int n_in,
                              void* d_out, int out_size, void* d_ws, size_t ws_size,
                              hipStream_t stream)
{
    (void)in_sizes; (void)n_in; (void)out_size; (void)ws_size;
    const float* emb = (const float*)d_in[0];
    const int*   tgt = (const int*)d_in[1];
    float*       out = (float*)d_out;

    uint32_t* a8  = (uint32_t*)d_ws;                                  // 2 MB
    uint32_t* b8  = a8 + (size_t)NROWS * 64;                          // 2 MB
    float*    pts = (float*)(b8 + (size_t)NROWS * 64);                // 1 MB
    float*    sp  = pts + (size_t)NG * NROWS;                         // 32 KB

    normalize_kernel<<<NROWS / 4, 256, 0, stream>>>(emb, a8, b8, out);

    fused_kernel<<<NCLS + NIT * NG, 256, 0, stream>>>(
        (const uint8_t*)a8, (const uint8_t*)b8, tgt, pts, sp);

    finalize_kernel<<<NROWS / 256, 256, 0, stream>>>(pts, sp, out);
}

// Round 7
// 107.818 us; speedup vs baseline: 1.2670x; 1.2670x over previous
//
#include <hip/hip_runtime.h>
#include <hip/hip_bf16.h>
#include <stdint.h>
#include <math.h>

#define NROWS 8192
#define DIM   256
#define RB    256          // row bytes (fp8)
#define BI    128          // i rows per tile
#define JSUB  64           // j rows per phase (LDS double-buffered)
#define NBJS  4
#define JBLK  (JSUB*NBJS)  // 256 j rows per tile
#define NG    (NROWS/JBLK) // 32 row-sum slabs
#define NCLS  64
#define CAP   256          // max class members (mean 128)
#define NTILE 1056         // kept tiles: sum_{jg<32}(2jg+2) ; upper 992 + diag 64

typedef __attribute__((ext_vector_type(4)))  int   int4v;
typedef __attribute__((ext_vector_type(8)))  int   int8v;
typedef __attribute__((ext_vector_type(16))) float floatx16;

typedef const __attribute__((address_space(1))) uint32_t gas_u32;
typedef __attribute__((address_space(3))) uint32_t las_u32;

#define SCALE_1_16 0x7B7B7B7B          // E8M0 123 = 2^-4 in every byte
#define L2E10      14.4269504088896f   // 10 * log2(e)
#define CA_SCALE   (L2E10 * 16.0f)     // A-side fp8 pre-scale
#define CB_SCALE   16.0f               // B-side fp8 pre-scale; CA*CB*2^-8 = L2E10
                                       // (symmetric product -> operand swap exact)

#if __has_builtin(__builtin_amdgcn_exp2f)
#define EXP2(x) __builtin_amdgcn_exp2f(x)   // raw v_exp_f32; inputs <= 14.43, safe
#else
#define EXP2(x) exp2f(x)
#endif

__device__ __forceinline__ void gload_lds16(const void* g, void* l) {
    // LDS dest = wave-uniform base + lane*16 ; global src per-lane
    __builtin_amdgcn_global_load_lds((gas_u32*)(uintptr_t)g,
                                     (las_u32*)(uintptr_t)l, 16, 0, 0);
}

// ---- Kernel 1: row-normalize fp32 -> two fp8 e4m3 arrays ----
__global__ __launch_bounds__(256) void normalize_kernel(const float* __restrict__ emb,
                                                        uint32_t* __restrict__ a8,
                                                        uint32_t* __restrict__ b8,
                                                        float* __restrict__ out)
{
    if (blockIdx.x == 0 && threadIdx.x == 0) *out = 0.f;   // replaces memset dispatch
    int row  = blockIdx.x * 4 + (threadIdx.x >> 6);
    int lane = threadIdx.x & 63;
    float4 v = ((const float4*)(emb + (size_t)row * DIM))[lane];
    float ss = v.x*v.x + v.y*v.y + v.z*v.z + v.w*v.w;
    #pragma unroll
    for (int off = 32; off > 0; off >>= 1)
        ss += __shfl_xor(ss, off, 64);
    float inv = 1.0f / fmaxf(sqrtf(ss), 1e-8f);
    float ia = CA_SCALE * inv, ib = CB_SCALE * inv;
    int ra = __builtin_amdgcn_cvt_pk_fp8_f32(v.x * ia, v.y * ia, 0, false);
    ra     = __builtin_amdgcn_cvt_pk_fp8_f32(v.z * ia, v.w * ia, ra, true);
    int rb = __builtin_amdgcn_cvt_pk_fp8_f32(v.x * ib, v.y * ib, 0, false);
    rb     = __builtin_amdgcn_cvt_pk_fp8_f32(v.z * ib, v.w * ib, rb, true);
    a8[(size_t)row * 64 + lane] = (uint32_t)ra;
    b8[(size_t)row * 64 + lane] = (uint32_t)rb;
}

// ---- Kernel 2 (fused): blocks 0..63 = per-class positives; blocks 64+ =
//      upper-triangle tiles. Upper tiles also emit transposed (column) sums
//      via operand-swapped MFMA on the SAME registers -> delivery halved. ----
template<bool DIAG>
__device__ __forceinline__ void epi(const floatx16 acc[2],
                                    int jbs, int h, int ic0, float& ts)
{
    #pragma unroll
    for (int jt = 0; jt < 2; ++jt)
        #pragma unroll
        for (int rq = 0; rq < 4; ++rq)
            #pragma unroll
            for (int r2 = 0; r2 < 4; ++r2) {
                float v = EXP2(acc[jt][rq * 4 + r2]);   // acc already = L2E10*cos
                if (DIAG) {
                    const int jg_ = jbs + jt * 32 + rq * 8 + h * 4 + r2;
                    if (jg_ == ic0) v = 0.f;            // exclude diagonal
                }
                ts += v;
            }
}

__global__ __launch_bounds__(256, 4) void fused_kernel(const uint8_t* __restrict__ eA,
                                                       const uint8_t* __restrict__ eB,
                                                       const int* __restrict__ tgt,
                                                       float* __restrict__ pts,
                                                       float* __restrict__ sp)
{
    __shared__ uint8_t smem[2 * JSUB * RB];   // 32 KB: tile A dbuf / pos idx scratch
    __shared__ float   cs4[4][JBLK];          // 4 KB: per-wave column-sum slabs

    const int tid  = threadIdx.x;
    const int wave = tid >> 6;
    const int lane = tid & 63;
    const int col  = lane & 31;
    const int h    = lane >> 5;

    if (blockIdx.x < NCLS) {
        // ================= positives path (one block per class) =================
        int* idx = (int*)smem;
        int* cnt = (int*)(smem + CAP * 4);
        const int c = blockIdx.x;
        if (tid == 0) *cnt = 0;
        __syncthreads();
        int4v tv[8];
        #pragma unroll
        for (int k = 0; k < 8; ++k)
            tv[k] = *(const int4v*)(tgt + k * 1024 + tid * 4);
        #pragma unroll
        for (int k = 0; k < 8; ++k)
            #pragma unroll
            for (int r = 0; r < 4; ++r)
                if (tv[k][r] == c) {
                    int p = atomicAdd(cnt, 1);
                    if (p < CAP) idx[p] = k * 1024 + tid * 4 + r;
                }
        __syncthreads();
        const int M   = min(*cnt, CAP);
        const int Mp  = (M + 31) & ~31;
        const int nbt = Mp >> 5;

        for (int bt = wave; bt < nbt; bt += 4) {
            const int b = bt * 32 + col;
            const uint8_t* pb = eB + (size_t)idx[min(b, M - 1)] * RB + h * 32;
            int8v bfr[4];
            #pragma unroll
            for (int s = 0; s < 4; ++s)
                bfr[s] = *(const int8v*)(pb + s * 64);
            float psum = 0.f;
            for (int at = 0; at < nbt; ++at) {
                const uint8_t* pa = eA + (size_t)idx[min(at * 32 + col, M - 1)] * RB + h * 32;
                floatx16 acc = (floatx16){0.f,0.f,0.f,0.f,0.f,0.f,0.f,0.f,
                                          0.f,0.f,0.f,0.f,0.f,0.f,0.f,0.f};
                #pragma unroll
                for (int s = 0; s < 4; ++s) {
                    int8v af = *(const int8v*)(pa + s * 64);
                    acc = __builtin_amdgcn_mfma_scale_f32_32x32x64_f8f6f4(
                        af, bfr[s], acc, 0, 0, 0, SCALE_1_16, 0, SCALE_1_16);
                }
                #pragma unroll
                for (int rq = 0; rq < 4; ++rq)
                    #pragma unroll
                    for (int r2 = 0; r2 < 4; ++r2) {
                        const int a = at * 32 + rq * 8 + h * 4 + r2;
                        float v = EXP2(acc[rq * 4 + r2]);
                        psum += (a != b && a < M) ? v : 0.f;
                    }
            }
            psum += __shfl_xor(psum, 32, 64);
            if (h == 0 && b < M) sp[idx[b]] = psum;
        }
        return;
    }

    // ================= upper-triangle tile path =================
    // tile list: g -> (jg, bi) with bi in [0, 2jg+2); bi<2jg strictly-upper,
    // bi in {2jg, 2jg+1} diagonal. cum(jg) = jg*(jg+1).
    const int g = blockIdx.x - NCLS;
    int jg = (int)((sqrtf((float)(4 * g + 1)) - 1.f) * 0.5f);
    while ((jg + 1) * (jg + 2) <= g) ++jg;
    while (jg * (jg + 1) > g) --jg;
    const int bi      = g - jg * (jg + 1);
    const bool upper  = (bi < 2 * jg);
    const int  d      = bi - 2 * jg;     // diag phase pair selector (if !upper)

    // B fragments (i rows) straight from global to registers, once per block
    const uint8_t* pb = eB + (size_t)(bi * BI + wave * 32 + col) * RB + h * 32;
    int8v bfr[4];
    #pragma unroll
    for (int s = 0; s < 4; ++s)
        bfr[s] = *(const int8v*)(pb + s * 64);

    // A staging map (mod-16 xor swizzle on 16B chunks of 256B rows), 16 KB/stage
    int goffA[4];
    #pragma unroll
    for (int t = 0; t < 4; ++t) {
        int s   = wave * 256 + t * 64 + lane;
        int row = s >> 4;
        int lc  = (s & 15) ^ (row & 15);
        goffA[t] = row * RB + lc * 16;
    }
    const char* gA = (const char*)(eA + (size_t)jg * JBLK * RB);

    #pragma unroll
    for (int t = 0; t < 4; ++t)
        gload_lds16(gA + goffA[t], smem + wave * 4096 + t * 1024);

    const int ic0 = bi * BI + wave * 32 + col;   // this lane's i

    const int xm = col & 15;
    int poff[4];
    #pragma unroll
    for (int s = 0; s < 4; ++s)
        poff[s] = ((s * 4 + h * 2) ^ xm) << 4;   // partner chunk = poff[s]^16

    __syncthreads();   // drains A0 DMA

    float ts = 0.f;

    #pragma unroll
    for (int bjs = 0; bjs < NBJS; ++bjs) {
        if (bjs < NBJS - 1) {
            const char* gAn = gA + (size_t)(bjs + 1) * JSUB * RB;
            #pragma unroll
            for (int t = 0; t < 4; ++t)
                gload_lds16(gAn + goffA[t],
                            smem + ((bjs + 1) & 1) * (JSUB * RB) + wave * 4096 + t * 1024);
        }

        const uint8_t* ab = smem + (bjs & 1) * (JSUB * RB);
        floatx16 acc[2], acc2[2];
        #pragma unroll
        for (int jt = 0; jt < 2; ++jt) {
            acc[jt]  = (floatx16){0.f,0.f,0.f,0.f,0.f,0.f,0.f,0.f,
                                  0.f,0.f,0.f,0.f,0.f,0.f,0.f,0.f};
            acc2[jt] = acc[jt];
        }

        #pragma unroll
        for (int s = 0; s < 4; ++s) {
            #pragma unroll
            for (int jt = 0; jt < 2; ++jt) {
                const uint8_t* pa = ab + (size_t)(jt * 32 + col) * RB;
                int4v lo = *(const int4v*)(pa + poff[s]);
                int4v hi = *(const int4v*)(pa + (poff[s] ^ 16));
                int8v af = __builtin_shufflevector(lo, hi, 0, 1, 2, 3, 4, 5, 6, 7);
                // D[j][i]: rows from A = j-rows (regs), cols from B = i-rows (lanes)
                acc[jt] = __builtin_amdgcn_mfma_scale_f32_32x32x64_f8f6f4(
                    af, bfr[s], acc[jt], 0, 0, 0, SCALE_1_16, 0, SCALE_1_16);
                if (upper)   // transposed tile on the SAME registers: D2[i][j]
                    acc2[jt] = __builtin_amdgcn_mfma_scale_f32_32x32x64_f8f6f4(
                        bfr[s], af, acc2[jt], 0, 0, 0, SCALE_1_16, 0, SCALE_1_16);
            }
        }

        const int jbs = jg * JBLK + bjs * JSUB;
        if (upper) {
            epi<false>(acc, jbs, h, ic0, ts);
            // column sums: acc2 col = lane -> j = jbs_local + jt*32 + col;
            // regs span 16 i's of this h-half; xor32 adds the other half.
            #pragma unroll
            for (int jt = 0; jt < 2; ++jt) {
                float cp = 0.f;
                #pragma unroll
                for (int k = 0; k < 16; ++k)
                    cp += EXP2(acc2[jt][k]);
                cp += __shfl_xor(cp, 32, 64);
                if (h == 0)
                    cs4[wave][bjs * JSUB + jt * 32 + col] = cp;
            }
        } else {
            if ((bjs >> 1) == d)
                epi<true >(acc, jbs, h, ic0, ts);
            else
                epi<false>(acc, jbs, h, ic0, ts);
        }

        if (bjs < NBJS - 1)
            __syncthreads();
    }

    ts += __shfl_xor(ts, 32, 64);
    if (h == 0)
        pts[(size_t)jg * NROWS + ic0] = ts;

    if (upper) {   // flush column sums: rows jg*256.. into col-slab NG+bi
        __syncthreads();
        float c = cs4[0][tid] + cs4[1][tid] + cs4[2][tid] + cs4[3][tid];
        pts[(size_t)(NG + bi) * NROWS + jg * JBLK + tid] = c;
    }
}

// ---- Kernel 3: per-row log-diff + global sum ----
// row r: row-slabs t in [r>>8, 32)  +  col-slabs bi in [0, 2*(r>>8)).
// Coverage is exact; unwritten slab entries are never read.
__global__ __launch_bounds__(256) void finalize_kernel(const float* __restrict__ pts,
                                                       const float* __restrict__ sp,
                                                       float* __restrict__ out)
{
    const int jgr = blockIdx.x;                 // uniform per block: i>>8
    const int i   = blockIdx.x * 256 + threadIdx.x;
    float st = 0.f;
    for (int t = jgr; t < NG; ++t)
        st += pts[(size_t)t * NROWS + i];
    for (int b = 0; b < 2 * jgr; ++b)
        st += pts[(size_t)(NG + b) * NROWS + i];
    const float spv = sp[i];
    const float ns  = st - spv;          // negatives = total - positives
    float loss = logf(ns) - logf(spv);
    #pragma unroll
    for (int off = 32; off > 0; off >>= 1)
        loss += __shfl_xor(loss, off, 64);
    __shared__ float w4[4];
    if ((threadIdx.x & 63) == 0) w4[threadIdx.x >> 6] = loss;
    __syncthreads();
    if (threadIdx.x == 0)
        atomicAdd(out, w4[0] + w4[1] + w4[2] + w4[3]);
}

extern "C" void kernel_launch(void* const* d_in, const int* in_sizes, int n_in,
                              void* d_out, int out_size, void* d_ws, size_t ws_size,
                              hipStream_t stream)
{
    (void)in_sizes; (void)n_in; (void)out_size; (void)ws_size;
    const float* emb = (const float*)d_in[0];
    const int*   tgt = (const int*)d_in[1];
    float*       out = (float*)d_out;

    uint32_t* a8  = (uint32_t*)d_ws;                                  // 2 MB
    uint32_t* b8  = a8 + (size_t)NROWS * 64;                          // 2 MB
    float*    pts = (float*)(b8 + (size_t)NROWS * 64);                // 3 MB (96 slabs)
    float*    sp  = pts + (size_t)(NG + 64) * NROWS;                  // 32 KB

    normalize_kernel<<<NROWS / 4, 256, 0, stream>>>(emb, a8, b8, out);

    fused_kernel<<<NCLS + NTILE, 256, 0, stream>>>(
        (const uint8_t*)a8, (const uint8_t*)b8, tgt, pts, sp);

    finalize_kernel<<<NROWS / 256, 256, 0, stream>>>(pts, sp, out);
}

// Round 8
// 83.458 us; speedup vs baseline: 1.6367x; 1.2919x over previous
//
#include <hip/hip_runtime.h>
#include <hip/hip_bf16.h>
#include <stdint.h>
#include <math.h>

#define NROWS 8192
#define DIM   256
#define RB    256          // row bytes (fp8)
#define BI    128          // i rows per tile block
#define JSUB  64           // j rows per sub-tile (LDS double-buffered)
#define NBJS  8
#define JBLK  (JSUB*NBJS)  // 512 j rows per tile block
#define NG    (NROWS/JBLK) // 16
#define NIT   (NROWS/BI)   // 64
#define NCLS  64
#define CAP   256          // max class members (mean 128)

typedef __attribute__((ext_vector_type(4)))  int   int4v;
typedef __attribute__((ext_vector_type(8)))  int   int8v;
typedef __attribute__((ext_vector_type(16))) float floatx16;

typedef const __attribute__((address_space(1))) uint32_t gas_u32;
typedef __attribute__((address_space(3))) uint32_t las_u32;

#define SCALE_1_16 0x7B7B7B7B          // E8M0 123 = 2^-4 in every byte
#define L2E10      14.4269504088896f   // 10 * log2(e)
#define CA_SCALE   (L2E10 * 16.0f)     // A-side fp8 pre-scale -> acc = L2E10*cos
#define CB_SCALE   16.0f               // B-side fp8 pre-scale

#if __has_builtin(__builtin_amdgcn_exp2f)
#define EXP2(x) __builtin_amdgcn_exp2f(x)   // raw v_exp_f32; inputs <= 14.43, safe
#else
#define EXP2(x) exp2f(x)
#endif

__device__ __forceinline__ void gload_lds16(const void* g, void* l) {
    // LDS dest = wave-uniform base + lane*16 ; global src per-lane
    __builtin_amdgcn_global_load_lds((gas_u32*)(uintptr_t)g,
                                     (las_u32*)(uintptr_t)l, 16, 0, 0);
}

// ---- Kernel 1: row-normalize fp32 -> two fp8 e4m3 arrays (A: x230.83, B: x16) ----
// acc = (CA*e_j)*(CB*e_i)*2^-8 = 14.4269*cos  -> epilogue needs no fma, no offset.
__global__ __launch_bounds__(256) void normalize_kernel(const float* __restrict__ emb,
                                                        uint32_t* __restrict__ a8,
                                                        uint32_t* __restrict__ b8,
                                                        float* __restrict__ out)
{
    if (blockIdx.x == 0 && threadIdx.x == 0) *out = 0.f;   // replaces memset dispatch
    int row  = blockIdx.x * 4 + (threadIdx.x >> 6);
    int lane = threadIdx.x & 63;
    float4 v = ((const float4*)(emb + (size_t)row * DIM))[lane];
    float ss = v.x*v.x + v.y*v.y + v.z*v.z + v.w*v.w;
    #pragma unroll
    for (int off = 32; off > 0; off >>= 1)
        ss += __shfl_xor(ss, off, 64);
    float inv = 1.0f / fmaxf(sqrtf(ss), 1e-8f);
    float ia = CA_SCALE * inv, ib = CB_SCALE * inv;
    int ra = __builtin_amdgcn_cvt_pk_fp8_f32(v.x * ia, v.y * ia, 0, false);
    ra     = __builtin_amdgcn_cvt_pk_fp8_f32(v.z * ia, v.w * ia, ra, true);
    int rb = __builtin_amdgcn_cvt_pk_fp8_f32(v.x * ib, v.y * ib, 0, false);
    rb     = __builtin_amdgcn_cvt_pk_fp8_f32(v.z * ib, v.w * ib, rb, true);
    a8[(size_t)row * 64 + lane] = (uint32_t)ra;
    b8[(size_t)row * 64 + lane] = (uint32_t)rb;
}

// ---- Kernel 2 (fused): blocks 0..63 = per-class positives; blocks 64+ = neg/total tiles ----
template<bool DIAG>
__device__ __forceinline__ void epi(const floatx16 acc[2],
                                    int jbs, int h, int ic0, float& ts)
{
    #pragma unroll
    for (int jt = 0; jt < 2; ++jt)
        #pragma unroll
        for (int rq = 0; rq < 4; ++rq)
            #pragma unroll
            for (int r2 = 0; r2 < 4; ++r2) {
                float v = EXP2(acc[jt][rq * 4 + r2]);   // acc already = L2E10*cos
                if (DIAG) {
                    const int jg_ = jbs + jt * 32 + rq * 8 + h * 4 + r2;
                    if (jg_ == ic0) v = 0.f;            // exclude diagonal
                }
                ts += v;
            }
}

__global__ __launch_bounds__(256, 4) void fused_kernel(const uint8_t* __restrict__ eA,
                                                       const uint8_t* __restrict__ eB,
                                                       const int* __restrict__ tgt,
                                                       float* __restrict__ pts,
                                                       float* __restrict__ sp)
{
    __shared__ uint8_t smem[2 * JSUB * RB];   // 32 KB: tile A dbuf / pos idx scratch

    const int tid  = threadIdx.x;
    const int wave = tid >> 6;
    const int lane = tid & 63;
    const int col  = lane & 31;
    const int h    = lane >> 5;

    if (blockIdx.x < NCLS) {
        // ================= positives path (one block per class) =================
        int* idx = (int*)smem;
        int* cnt = (int*)(smem + CAP * 4);
        const int c = blockIdx.x;
        if (tid == 0) *cnt = 0;
        __syncthreads();
        // scan all targets (coalesced int4 loads, batched for latency)
        int4v tv[8];
        #pragma unroll
        for (int k = 0; k < 8; ++k)
            tv[k] = *(const int4v*)(tgt + k * 1024 + tid * 4);
        #pragma unroll
        for (int k = 0; k < 8; ++k)
            #pragma unroll
            for (int r = 0; r < 4; ++r)
                if (tv[k][r] == c) {
                    int p = atomicAdd(cnt, 1);
                    if (p < CAP) idx[p] = k * 1024 + tid * 4 + r;
                }
        __syncthreads();
        const int M   = min(*cnt, CAP);
        const int Mp  = (M + 31) & ~31;
        const int nbt = Mp >> 5;

        // fragments straight from L2 (f8f6f4 layout: lane row=col, k [s*64+h*32,+32))
        for (int bt = wave; bt < nbt; bt += 4) {
            const int b = bt * 32 + col;
            const uint8_t* pb = eB + (size_t)idx[min(b, M - 1)] * RB + h * 32;
            int8v bfr[4];
            #pragma unroll
            for (int s = 0; s < 4; ++s)
                bfr[s] = *(const int8v*)(pb + s * 64);
            float psum = 0.f;
            for (int at = 0; at < nbt; ++at) {
                const uint8_t* pa = eA + (size_t)idx[min(at * 32 + col, M - 1)] * RB + h * 32;
                floatx16 acc = (floatx16){0.f,0.f,0.f,0.f,0.f,0.f,0.f,0.f,
                                          0.f,0.f,0.f,0.f,0.f,0.f,0.f,0.f};
                #pragma unroll
                for (int s = 0; s < 4; ++s) {
                    int8v af = *(const int8v*)(pa + s * 64);
                    acc = __builtin_amdgcn_mfma_scale_f32_32x32x64_f8f6f4(
                        af, bfr[s], acc, 0, 0, 0, SCALE_1_16, 0, SCALE_1_16);
                }
                #pragma unroll
                for (int rq = 0; rq < 4; ++rq)
                    #pragma unroll
                    for (int r2 = 0; r2 < 4; ++r2) {
                        const int a = at * 32 + rq * 8 + h * 4 + r2;
                        float v = EXP2(acc[rq * 4 + r2]);
                        psum += (a != b && a < M) ? v : 0.f;   // exact diag/pad mask
                    }
            }
            psum += __shfl_xor(psum, 32, 64);   // h-halves: disjoint a's, same b
            if (h == 0 && b < M) sp[idx[b]] = psum;
        }
        return;
    }

    // ================= negatives/total tile path =================
    const int g  = blockIdx.x - NCLS;
    const int bi = g & (NIT - 1);
    const int jg = g >> 6;

    // B fragments straight from global to registers, once per block (L2-hit)
    const uint8_t* pb = eB + (size_t)(bi * BI + wave * 32 + col) * RB + h * 32;
    int8v bfr[4];
    #pragma unroll
    for (int s = 0; s < 4; ++s)
        bfr[s] = *(const int8v*)(pb + s * 64);

    // A staging map (mod-16 xor swizzle on 16B chunks of 256B rows)
    int goffA[4];
    #pragma unroll
    for (int t = 0; t < 4; ++t) {
        int s   = wave * 256 + t * 64 + lane;
        int row = s >> 4;
        int lc  = (s & 15) ^ (row & 15);
        goffA[t] = row * RB + lc * 16;
    }
    const char* gA = (const char*)(eA + (size_t)jg * JBLK * RB);

    #pragma unroll
    for (int t = 0; t < 4; ++t)
        gload_lds16(gA + goffA[t], smem + wave * 4096 + t * 1024);

    const int ic0 = bi * BI + wave * 32 + col;   // this lane's i

    const int xm = col & 15;
    int poff[4];
    #pragma unroll
    for (int s = 0; s < 4; ++s)
        poff[s] = ((s * 4 + h * 2) ^ xm) << 4;   // partner chunk = poff[s]^16

    __syncthreads();   // drains A0 DMA

    float ts = 0.f;
    const int dpair = bi - jg * 4;   // sub-tile pair touching the diagonal (if 0..3)

    #pragma unroll
    for (int bjs = 0; bjs < NBJS; ++bjs) {
        if (bjs < NBJS - 1) {   // issue next A stage; drains at phase-end barrier
            const char* gAn = gA + (size_t)(bjs + 1) * JSUB * RB;
            #pragma unroll
            for (int t = 0; t < 4; ++t)
                gload_lds16(gAn + goffA[t],
                            smem + ((bjs + 1) & 1) * (JSUB * RB) + wave * 4096 + t * 1024);
        }

        const uint8_t* ab = smem + (bjs & 1) * (JSUB * RB);
        floatx16 acc[2];
        #pragma unroll
        for (int jt = 0; jt < 2; ++jt)
            acc[jt] = (floatx16){0.f,0.f,0.f,0.f,0.f,0.f,0.f,0.f,
                                 0.f,0.f,0.f,0.f,0.f,0.f,0.f,0.f};

        #pragma unroll
        for (int s = 0; s < 4; ++s) {
            int8v af[2];
            #pragma unroll
            for (int jt = 0; jt < 2; ++jt) {
                const uint8_t* pa = ab + (size_t)(jt * 32 + col) * RB;
                int4v lo = *(const int4v*)(pa + poff[s]);
                int4v hi = *(const int4v*)(pa + (poff[s] ^ 16));
                af[jt] = __builtin_shufflevector(lo, hi, 0, 1, 2, 3, 4, 5, 6, 7);
            }
            #pragma unroll
            for (int jt = 0; jt < 2; ++jt)
                acc[jt] = __builtin_amdgcn_mfma_scale_f32_32x32x64_f8f6f4(
                    af[jt], bfr[s], acc[jt], 0, 0,
                    0, SCALE_1_16, 0, SCALE_1_16);
        }

        const int jbs = jg * JBLK + bjs * JSUB;
        if ((bjs >> 1) == dpair)
            epi<true >(acc, jbs, h, ic0, ts);
        else
            epi<false>(acc, jbs, h, ic0, ts);

        if (bjs < NBJS - 1)
            __syncthreads();   // drains next-A DMA; guards restage of buffer just read
    }

    ts += __shfl_xor(ts, 32, 64);   // L and L+32: same i, disjoint j-halves
    if (h == 0)
        pts[(size_t)jg * NROWS + ic0] = ts;
}

// ---- Kernel 3: per-row log-diff + global sum ----
__global__ __launch_bounds__(256) void finalize_kernel(const float* __restrict__ pts,
                                                       const float* __restrict__ sp,
                                                       float* __restrict__ out)
{
    const int i = blockIdx.x * 256 + threadIdx.x;
    float st = 0.f;
    #pragma unroll
    for (int t = 0; t < NG; ++t)
        st += pts[(size_t)t * NROWS + i];
    const float spv = sp[i];
    const float ns  = st - spv;          // negatives = total - positives (diag-free both)
    float loss = logf(ns) - logf(spv);
    #pragma unroll
    for (int off = 32; off > 0; off >>= 1)
        loss += __shfl_xor(loss, off, 64);
    __shared__ float w4[4];
    if ((threadIdx.x & 63) == 0) w4[threadIdx.x >> 6] = loss;
    __syncthreads();
    if (threadIdx.x == 0)
        atomicAdd(out, w4[0] + w4[1] + w4[2] + w4[3]);
}

extern "C" void kernel_launch(void* const* d_in, const int* in_sizes, int n_in,
                              void* d_out, int out_size, void* d_ws, size_t ws_size,
                              hipStream_t stream)
{
    (void)in_sizes; (void)n_in; (void)out_size; (void)ws_size;
    const float* emb = (const float*)d_in[0];
    const int*   tgt = (const int*)d_in[1];
    float*       out = (float*)d_out;

    uint32_t* a8  = (uint32_t*)d_ws;                                  // 2 MB
    uint32_t* b8  = a8 + (size_t)NROWS * 64;                          // 2 MB
    float*    pts = (float*)(b8 + (size_t)NROWS * 64);                // 512 KB
    float*    sp  = pts + (size_t)NG * NROWS;                         // 32 KB

    normalize_kernel<<<NROWS / 4, 256, 0, stream>>>(emb, a8, b8, out);

    fused_kernel<<<NCLS + NIT * NG, 256, 0, stream>>>(
        (const uint8_t*)a8, (const uint8_t*)b8, tgt, pts, sp);

    finalize_kernel<<<NROWS / 256, 256, 0, stream>>>(pts, sp, out);
}